// Round 9
// baseline (247.761 us; speedup 1.0000x reference)
//
#include <hip/hip_runtime.h>
#include <hip/hip_bf16.h>

#define NN 32768   // nodes
#define BB 64      // graphs
#define MM 512     // nodes per graph
#define HH 4       // heads
#define DD 64      // head dim
#define INF 256    // input features
#define HD 256     // H*D
#define EE 524288  // edges

typedef unsigned short ushort;
typedef unsigned int uint;
typedef short s16x8 __attribute__((ext_vector_type(8)));
typedef ushort u16x8 __attribute__((ext_vector_type(8)));
typedef float f32x4 __attribute__((ext_vector_type(4)));

__device__ __forceinline__ ushort f2bf(float f) {
    uint u = __float_as_uint(f);
    return (ushort)((u + 0x7fffu + ((u >> 16) & 1u)) >> 16);
}
__device__ __forceinline__ float bf2f(ushort u) {
    return __uint_as_float((uint)u << 16);
}
__device__ __forceinline__ uint pkbf(float x, float y) {
    __hip_bfloat162 h = __float22bfloat162_rn(make_float2(x, y));
    return *(uint*)&h;
}

#define GLD16(gp, lp) __builtin_amdgcn_global_load_lds( \
    (const __attribute__((address_space(1))) void*)(gp), \
    (__attribute__((address_space(3))) void*)(lp), 16, 0, 0)

// ---------------------------------------------------------------------------
// K1: convert_w (blocks 0..767) ∪ deg histogram (blocks 768..2815).
// ---------------------------------------------------------------------------
__global__ __launch_bounds__(256) void prep_kernel(
    const float* __restrict__ Wq, const float* __restrict__ Wk,
    const float* __restrict__ Wv, ushort* __restrict__ WT,
    const int* __restrict__ ei, int* __restrict__ deg)
{
    const int bid = blockIdx.x;
    if (bid < 768) {
        const int id = bid * 256 + threadIdx.x;      // 3*65536
        const int mat = id >> 16, rem = id & 65535;
        const int n = rem >> 8, kk = rem & 255;
        const float* W = (mat == 0) ? Wq : (mat == 1) ? Wk : Wv;
        WT[id] = f2bf(W[kk * 256 + n]);              // WT[mat][n][kk]
    } else {
        const int e = (bid - 768) * 256 + threadIdx.x;   // EE total
        atomicAdd(&deg[ei[EE + e]], 1);
    }
}

// ---------------------------------------------------------------------------
// K2: qkv GEMM (blocks 0..1535) ∪ scan (block 1536).
// A: f32 global->reg -> cvt_pk bf16 -> ds_write (2-buffer). B: bf16
// global_load_lds (3-buffer). ALL compute-needed vmcnt waits are BEFORE
// the barrier (race-free cross-wave: gld_lds completion is per-wave, so
// readers of other waves' staging rely on pre-barrier waits). Steady
// state: vmcnt(2) at iter top completes A(cur)+B(cur); B keeps 2 iters
// of flight. LDS = exactly 40 KB (part/wred aliased into As/Bs; disjoint
// lifetimes) -> 4 blocks/CU (was 3).
// ---------------------------------------------------------------------------
__global__ __launch_bounds__(256) void qkv_scan(
    const float* __restrict__ Xq, const float* __restrict__ Xs,
    const ushort* __restrict__ WT,
    const float* __restrict__ bq, const float* __restrict__ bk,
    const float* __restrict__ bv,
    ushort* __restrict__ qo, ushort* __restrict__ ko, ushort* __restrict__ vo,
    float* __restrict__ sumsq,
    const int* __restrict__ deg, int* __restrict__ offsets)
{
    __shared__ ushort As[2][128 * 32];
    __shared__ ushort Bs[3][128 * 32];
    // aliases with disjoint lifetimes (keep LDS at exactly 40 KB):
    int*   part = (int*)&As[0][0];     // scan path only (never runs GEMM)
    float* wred = (float*)&Bs[0][0];   // epilogue only (after last Bs[0] read)

    const int id = blockIdx.x;
    const int t = threadIdx.x;

    if (id == 1536) {   // exclusive scan of deg -> offsets, 128 elems/thread
        const int base = t * 128;
        int s = 0;
        for (int i = 0; i < 128; ++i) s += deg[base + i];
        part[t] = s;
        __syncthreads();
        for (int off = 1; off < 256; off <<= 1) {
            int a = part[t];
            int b2 = (t >= off) ? part[t - off] : 0;
            __syncthreads();
            part[t] = a + b2;
            __syncthreads();
        }
        int run = (t == 0) ? 0 : part[t - 1];
        for (int i = 0; i < 128; ++i) { offsets[base + i] = run; run += deg[base + i]; }
        if (t == 255) offsets[NN] = run;
        return;
    }

    const int vv = (id & 7) * 192 + (id >> 3);   // XCD-contiguous row-groups
    const int rt = vv / 6, ct = vv % 6;
    const int wsel = ct >> 1;                    // 0:q 1:k 2:v
    const float* A    = (wsel == 0) ? Xq : Xs;
    const ushort* W   = WT + (size_t)wsel * 65536;
    const float* bias = (wsel == 0) ? bq : (wsel == 1) ? bk : bv;
    ushort* C         = (wsel == 0) ? qo : (wsel == 1) ? ko : vo;
    const int row0 = rt * 128;
    const int col0 = (ct & 1) * 128;

    const int l = t & 63, w = t >> 6;
    const int fr = l & 15, q4 = l >> 4;
    const int wr = (w & 1) * 64, wc = (w >> 1) * 64;

    // staging geometry: per wave, 64 lanes; row = w*16 + l/4, K-chunk (l&3)*8
    const int srow = (w << 4) + (l >> 2);        // 0..63 within 64-row half
    const int scol = (l & 3) << 3;               // 0,8,16,24 (elems)
    const float*  ga = &A[(size_t)(row0 + srow) * INF + scol];
    const ushort* gb = &W[(size_t)(col0 + srow) * INF + scol];
    const int lbase = (w << 9);                  // wave-uniform ushort offset

    f32x4 acc[4][4] = {};
    float4 a00, a01, a10, a11;                   // A f32 staging regs

#define QKV_ALOAD(k0) { \
    const float* p0 = ga + (k0); \
    const float* p1 = ga + (k0) + 64 * INF; \
    a00 = *(const float4*)(p0);     a01 = *(const float4*)(p0 + 4); \
    a10 = *(const float4*)(p1);     a11 = *(const float4*)(p1 + 4); }

#define QKV_AWRITE(abuf) { \
    union { u16x8 v; uint u[4]; } c0, c1; \
    c0.u[0] = pkbf(a00.x, a00.y); c0.u[1] = pkbf(a00.z, a00.w); \
    c0.u[2] = pkbf(a01.x, a01.y); c0.u[3] = pkbf(a01.z, a01.w); \
    c1.u[0] = pkbf(a10.x, a10.y); c1.u[1] = pkbf(a10.z, a10.w); \
    c1.u[2] = pkbf(a11.x, a11.y); c1.u[3] = pkbf(a11.z, a11.w); \
    *(u16x8*)&As[abuf][srow * 32 + scol]        = c0.v; \
    *(u16x8*)&As[abuf][2048 + srow * 32 + scol] = c1.v; }

#define QKV_BSTAGE(bbuf, k0) \
    GLD16(gb + (k0),            &Bs[bbuf][lbase]); \
    GLD16(gb + (k0) + 64 * INF, &Bs[bbuf][2048 + lbase]);

#define QKV_COMPUTE(abuf, bbuf) { \
    const int kg = q4 * 8; \
    s16x8 af[4], bfr[4]; \
    _Pragma("unroll") \
    for (int i = 0; i < 4; ++i) \
        af[i] = *(const s16x8*)&As[abuf][(wr + i * 16 + fr) * 32 + kg]; \
    _Pragma("unroll") \
    for (int j = 0; j < 4; ++j) \
        bfr[j] = *(const s16x8*)&Bs[bbuf][(wc + j * 16 + fr) * 32 + kg]; \
    _Pragma("unroll") \
    for (int i = 0; i < 4; ++i) \
    _Pragma("unroll") \
        for (int j = 0; j < 4; ++j) \
            acc[i][j] = __builtin_amdgcn_mfma_f32_16x16x32_bf16( \
                af[i], bfr[j], acc[i][j], 0, 0, 0); }

#define WAITN(n) asm volatile("s_waitcnt vmcnt(" #n ")" ::: "memory")
#define LGKM0   asm volatile("s_waitcnt lgkmcnt(0)" ::: "memory")
#define BAR     __builtin_amdgcn_s_barrier()

    // prologue: A0(4) + B0(2) + B1(2) in flight = 8 outstanding
    QKV_ALOAD(0)
    QKV_BSTAGE(0, 0)
    QKV_BSTAGE(1, 32)

    // it0: [A0,B0,B1]=8 -> wait(2) completes A0+B0 (pre-barrier!)
    WAITN(2); QKV_AWRITE(0) LGKM0; BAR;
    QKV_ALOAD(32)  QKV_BSTAGE(2, 64)   QKV_COMPUTE(0, 0)
    // it1: [B1,A1,B2]=8 -> wait(2) completes B1+A1
    WAITN(2); QKV_AWRITE(1) LGKM0; BAR;
    QKV_ALOAD(64)  QKV_BSTAGE(0, 96)   QKV_COMPUTE(1, 1)
    // it2: [B2,A2,B0]=8 -> wait(2) completes B2+A2
    WAITN(2); QKV_AWRITE(0) LGKM0; BAR;
    QKV_ALOAD(96)  QKV_BSTAGE(1, 128)  QKV_COMPUTE(0, 2)
    // it3: [B0,A3,B1]=8 -> wait(2) completes B0+A3
    WAITN(2); QKV_AWRITE(1) LGKM0; BAR;
    QKV_ALOAD(128) QKV_BSTAGE(2, 160)  QKV_COMPUTE(1, 0)
    // it4: [B1,A4,B2]=8 -> wait(2) completes B1+A4
    WAITN(2); QKV_AWRITE(0) LGKM0; BAR;
    QKV_ALOAD(160) QKV_BSTAGE(0, 192)  QKV_COMPUTE(0, 1)
    // it5: [B2,A5,B0]=8 -> wait(2) completes B2+A5
    WAITN(2); QKV_AWRITE(1) LGKM0; BAR;
    QKV_ALOAD(192) QKV_BSTAGE(1, 224)  QKV_COMPUTE(1, 2)
    // it6: [B0,A6,B1]=8 -> wait(2) completes B0+A6
    WAITN(2); QKV_AWRITE(0) LGKM0; BAR;
    QKV_ALOAD(224)                     QKV_COMPUTE(0, 0)
    // it7: [B1,A7]=6 -> wait(0) drains
    WAITN(0); QKV_AWRITE(1) LGKM0; BAR;
    QKV_COMPUTE(1, 1)

    float loc = 0.f;
#pragma unroll
    for (int j = 0; j < 4; ++j) {
        const int colg = col0 + wc + j * 16 + fr;
        const float bj = bias[colg];
#pragma unroll
        for (int i = 0; i < 4; ++i) {
            const int rowg = row0 + wr + i * 16 + q4 * 4;
            const float cv0 = acc[i][j][0] + bj;
            const float cv1 = acc[i][j][1] + bj;
            const float cv2 = acc[i][j][2] + bj;
            const float cv3 = acc[i][j][3] + bj;
            loc += cv0 * cv0 + cv1 * cv1 + cv2 * cv2 + cv3 * cv3;
            const uint p01 = pkbf(cv0, cv1);
            const uint p23 = pkbf(cv2, cv3);
            C[(size_t)(rowg + 0) * HD + colg] = (ushort)p01;
            C[(size_t)(rowg + 1) * HD + colg] = (ushort)(p01 >> 16);
            C[(size_t)(rowg + 2) * HD + colg] = (ushort)p23;
            C[(size_t)(rowg + 3) * HD + colg] = (ushort)(p23 >> 16);
        }
    }
    if (wsel < 2) {
#pragma unroll
        for (int off = 32; off > 0; off >>= 1) loc += __shfl_down(loc, off, 64);
        __syncthreads();               // all As/Bs reads done before wred alias
        if (l == 0) wred[w] = loc;
        __syncthreads();
        if (t == 0) atomicAdd(&sumsq[wsel], wred[0] + wred[1] + wred[2] + wred[3]);
    }
}

// ---------------------------------------------------------------------------
// K3: kv full-pass MFMA (blocks 0..255: one (b,h), 8 chunks of 64 rows,
// in-register accumulation; 18.4 KB LDS) ∪ vbar (blocks 256..1279, 16B
// loads) ∪ bucket (blocks 1280..3327).
// ---------------------------------------------------------------------------
#define KVP 72
__global__ __launch_bounds__(256) void kv_vbar_bucket(
    const ushort* __restrict__ k16, const ushort* __restrict__ v16,
    ushort* __restrict__ kv16, float* __restrict__ ksum_f, float* __restrict__ vsum_f,
    float* __restrict__ vbar,
    const int* __restrict__ ei, const float* __restrict__ ew,
    const int* __restrict__ deg, const int* __restrict__ offsets,
    int* __restrict__ cursor, int2* __restrict__ pairbuf)
{
    __shared__ ushort kT[64 * KVP];
    __shared__ ushort vT[64 * KVP];
    const int bid = blockIdx.x;
    const int t = threadIdx.x;

    if (bid >= 1280) {   // bucket: CSR fill, packed int2 {row, val}
        const int e = (bid - 1280) * 256 + t;
        const int row = ei[e], col = ei[EE + e];
        const long long prod = (long long)deg[row] * (long long)deg[col];
        float val = 0.f;
        if (prod > 0) val = ew[e] * __frsqrt_rn((float)prod);
        const int pos = atomicAdd(&cursor[col], 1);
        pairbuf[offsets[col] + pos] = make_int2(row, __float_as_int(val));
        return;
    }
    if (bid >= 256) {    // vbar: mean over heads, 8 d/thread, 16B loads
        const int idx = (bid - 256) * 256 + t;   // NN*8 total
        const int n = idx >> 3, d0 = (idx & 7) * 8;
        const ushort* vr = &v16[(size_t)n * HD + d0];
        u16x8 v0 = *(const u16x8*)(vr);
        u16x8 v1 = *(const u16x8*)(vr + 64);
        u16x8 v2 = *(const u16x8*)(vr + 128);
        u16x8 v3 = *(const u16x8*)(vr + 192);
        float o[8];
#pragma unroll
        for (int j = 0; j < 8; ++j)
            o[j] = 0.25f * (bf2f(v0[j]) + bf2f(v1[j]) + bf2f(v2[j]) + bf2f(v3[j]));
        float* vb = &vbar[(size_t)n * DD + d0];
        *(float4*)(vb)     = make_float4(o[0], o[1], o[2], o[3]);
        *(float4*)(vb + 4) = make_float4(o[4], o[5], o[6], o[7]);
        return;
    }

    // ---- kv MFMA: one (b,h), all 512 rows in 8 chunks of 64 ----
    const int h = bid & 3, b = bid >> 2;
    const int l = t & 63, w = t >> 6;
    const size_t base = (size_t)b * MM * HD + (size_t)h * DD;

    const int fr = l & 15, q4 = l >> 4, kg = q4 * 8;
    const int wr2 = (w & 1) * 32, wc2 = (w >> 1) * 32;
    s16x8 ones;
#pragma unroll
    for (int i = 0; i < 8; ++i) ones[i] = (short)0x3F80;

    f32x4 acc[2][2] = {};
    f32x4 aks[2] = {};
    f32x4 avs[2] = {};

    // staging decomposition (constant across chunks)
    const int mat = t >> 7;
    const int rem = t & 127;
    const int dq  = rem >> 5;          // 0..3
    const int u   = rem & 31;          // row-pair index
    const int r0  = 2 * u;             // rows r0, r0+1 within chunk
    const int d0  = dq * 16;
    const ushort* src = mat ? v16 : k16;
    ushort* dst = mat ? vT : kT;

    for (int chunk = 0; chunk < 8; ++chunk) {
        const int m0 = chunk * 64;
        {   // transpose-stage 64 rows x 64 d (2 rows/thread, packed uint)
            const ushort* p0 = &src[base + (size_t)(m0 + r0) * HD + d0];
            const ushort* p1 = p0 + HD;
            u16x8 ra0 = *(const u16x8*)(p0);
            u16x8 ra1 = *(const u16x8*)(p0 + 8);
            u16x8 rb0 = *(const u16x8*)(p1);
            u16x8 rb1 = *(const u16x8*)(p1 + 8);
#pragma unroll
            for (int jj = 0; jj < 8; ++jj) {
                uint pk = (uint)ra0[jj] | ((uint)rb0[jj] << 16);
                *(uint*)&dst[(d0 + jj) * KVP + r0] = pk;
            }
#pragma unroll
            for (int jj = 0; jj < 8; ++jj) {
                uint pk = (uint)ra1[jj] | ((uint)rb1[jj] << 16);
                *(uint*)&dst[(d0 + 8 + jj) * KVP + r0] = pk;
            }
        }
        __syncthreads();

#pragma unroll
        for (int s = 0; s < 2; ++s) {
            const int mo = s * 32 + kg;
            s16x8 af[2], bf[2];
            af[0] = *(const s16x8*)&kT[(wr2 + fr) * KVP + mo];
            af[1] = *(const s16x8*)&kT[(wr2 + 16 + fr) * KVP + mo];
            bf[0] = *(const s16x8*)&vT[(wc2 + fr) * KVP + mo];
            bf[1] = *(const s16x8*)&vT[(wc2 + 16 + fr) * KVP + mo];
#pragma unroll
            for (int il = 0; il < 2; ++il)
#pragma unroll
                for (int jl = 0; jl < 2; ++jl)
                    acc[il][jl] = __builtin_amdgcn_mfma_f32_16x16x32_bf16(
                        af[il], bf[jl], acc[il][jl], 0, 0, 0);
#pragma unroll
            for (int il = 0; il < 2; ++il)
                aks[il] = __builtin_amdgcn_mfma_f32_16x16x32_bf16(
                    af[il], ones, aks[il], 0, 0, 0);
#pragma unroll
            for (int jl = 0; jl < 2; ++jl)
                avs[jl] = __builtin_amdgcn_mfma_f32_16x16x32_bf16(
                    ones, bf[jl], avs[jl], 0, 0, 0);
        }
        __syncthreads();   // protect LDS overwrite by next chunk
    }

    // epilogue: kv16 bf16 direct, transposed [dv][dk]
    ushort* kvb = &kv16[((size_t)b * HH + h) * 4096];
#pragma unroll
    for (int jl = 0; jl < 2; ++jl) {
        const int dv = wc2 + 16 * jl + fr;
#pragma unroll
        for (int il = 0; il < 2; ++il) {
            const int dk = wr2 + 16 * il + q4 * 4;
            uint2 pk = make_uint2(pkbf(acc[il][jl][0], acc[il][jl][1]),
                                  pkbf(acc[il][jl][2], acc[il][jl][3]));
            *(uint2*)&kvb[(size_t)dv * 64 + dk] = pk;
        }
    }
    float* ksb = &ksum_f[((size_t)b * HH + h) * 64];
    float* vsb = &vsum_f[((size_t)b * HH + h) * 64];
    if (wc2 == 0 && fr == 0) {
#pragma unroll
        for (int il = 0; il < 2; ++il)
#pragma unroll
            for (int m = 0; m < 4; ++m)
                ksb[wr2 + 16 * il + q4 * 4 + m] = aks[il][m];
    }
    if (wr2 == 0 && l < 16) {
        vsb[wc2 + l]      = avs[0][0];
        vsb[wc2 + 16 + l] = avs[1][0];
    }
}

// ---------------------------------------------------------------------------
// K5: attn via MFMA. All 4 heads' KV + sums staged once; all 256
// denominators in one phase; head loop pure MFMA+epilogue, 2 barriers.
// ---------------------------------------------------------------------------
#define AKP 72
__global__ __launch_bounds__(256) void attn_mfma(
    const ushort* __restrict__ q16, const ushort* __restrict__ kv16,
    const float* __restrict__ ksum_f, const float* __restrict__ vsum_f,
    const float* __restrict__ sumsq,
    const int* __restrict__ n_nodes, float* __restrict__ out)
{
    const int b = blockIdx.y;
    const int m0 = blockIdx.x * 64;
    const int t = threadIdx.x;
    const int l = t & 63, w = t >> 6;
    const int fr = l & 15, q4 = l >> 4;
    const int wn = (w & 1) * 32, wd = (w >> 1) * 32;

    __shared__ ushort kvbf[HH][64 * AKP];
    __shared__ float ksum_l[HH][64], vsum_l[HH][64], denom_l[HH][64];

    const float nn = (float)n_nodes[b];
    const float inv = 1.0f / (sqrtf(sumsq[0]) * sqrtf(sumsq[1]));

    {   // stage all heads: bf16 KV [dv][dk] + ksum/vsum
        const int dv = t >> 2, dk0 = (t & 3) * 16;
#pragma unroll
        for (int h = 0; h < HH; ++h) {
            const ushort* kvg = &kv16[((size_t)(b * HH + h)) * 4096 + dv * 64 + dk0];
            *(uint4*)&kvbf[h][dv * AKP + dk0]     = *(const uint4*)kvg;
            *(uint4*)&kvbf[h][dv * AKP + dk0 + 8] = *(const uint4*)(kvg + 8);
        }
        const int hh = t >> 6, dd = t & 63;
        ksum_l[hh][dd] = ksum_f[((size_t)(b * HH + hh)) * 64 + dd];
        vsum_l[hh][dd] = vsum_f[((size_t)(b * HH + hh)) * 64 + dd];
    }
    __syncthreads();

    {   // denominators, all heads at once: thread = (row r, head hh)
        const int r = t & 63, hh = t >> 6;
        const ushort* qr = &q16[((size_t)(b * MM + m0 + r)) * HD + hh * DD];
        float dsum = 0.f;
#pragma unroll
        for (int c = 0; c < 8; ++c) {
            u16x8 qv = *(const u16x8*)(qr + 8 * c);
#pragma unroll
            for (int j2 = 0; j2 < 8; ++j2)
                dsum += bf2f(qv[j2]) * ksum_l[hh][8 * c + j2];
        }
        denom_l[hh][r] = nn + inv * dsum;
    }
    __syncthreads();

    f32x4 acco[2][2] = {};
#pragma unroll
    for (int h = 0; h < HH; ++h) {
        f32x4 pacc[2][2] = {};
#pragma unroll
        for (int kx = 0; kx < 2; ++kx) {
            const int k0 = kx * 32;
            s16x8 af[2], bfr[2];
#pragma unroll
            for (int il = 0; il < 2; ++il)
                af[il] = *(const s16x8*)&q16[
                    ((size_t)(b * MM + m0 + wn + 16 * il + fr)) * HD + h * DD + k0 + q4 * 8];
#pragma unroll
            for (int jl = 0; jl < 2; ++jl)
                bfr[jl] = *(const s16x8*)&kvbf[h][(wd + 16 * jl + fr) * AKP + k0 + q4 * 8];
#pragma unroll
            for (int il = 0; il < 2; ++il)
#pragma unroll
                for (int jl = 0; jl < 2; ++jl)
                    pacc[il][jl] = __builtin_amdgcn_mfma_f32_16x16x32_bf16(
                        af[il], bfr[jl], pacc[il][jl], 0, 0, 0);
        }
#pragma unroll
        for (int il = 0; il < 2; ++il)
#pragma unroll
            for (int m = 0; m < 4; ++m) {
                const float rden = 0.25f / denom_l[h][wn + 16 * il + q4 * 4 + m];
#pragma unroll
                for (int jl = 0; jl < 2; ++jl) {
                    const int d = wd + 16 * jl + fr;
                    acco[il][jl][m] += (inv * pacc[il][jl][m] + vsum_l[h][d]) * rden;
                }
            }
    }

#pragma unroll
    for (int il = 0; il < 2; ++il)
#pragma unroll
        for (int m = 0; m < 4; ++m) {
            const size_t node = (size_t)b * MM + m0 + wn + 16 * il + q4 * 4 + m;
#pragma unroll
            for (int jl = 0; jl < 2; ++jl)
                out[node * DD + wd + 16 * jl + fr] = acco[il][jl][m];
        }
}

// ---------------------------------------------------------------------------
// K6: GCN gather, 32 threads/node (2 groups of 16 split even/odd edges,
// combine via shfl_xor 16).
// ---------------------------------------------------------------------------
__global__ __launch_bounds__(256) void gcn_gather(
    const int* __restrict__ offsets, const int2* __restrict__ pairbuf,
    const float* __restrict__ vbar, float* __restrict__ out)
{
    const int t = blockIdx.x * 256 + threadIdx.x;   // NN*32 threads
    const int n = t >> 5;
    const int g = t & 31;
    const int d4 = (g & 15) << 2;
    const int grp = g >> 4;
    const int s = offsets[n], e = offsets[n + 1];
    float ax = 0.f, ay = 0.f, az = 0.f, aw = 0.f;
    int i = s + grp;
    for (; i + 2 < e; i += 4) {   // two edges (stride-2 within group)
        const int2 p0 = pairbuf[i], p1 = pairbuf[i + 2];
        const float w0 = __int_as_float(p0.y), w1 = __int_as_float(p1.y);
        const float4 v0 = *(const float4*)&vbar[(size_t)p0.x * DD + d4];
        const float4 v1 = *(const float4*)&vbar[(size_t)p1.x * DD + d4];
        ax += w0 * v0.x + w1 * v1.x;
        ay += w0 * v0.y + w1 * v1.y;
        az += w0 * v0.z + w1 * v1.z;
        aw += w0 * v0.w + w1 * v1.w;
    }
    if (i < e) {
        const int2 p = pairbuf[i];
        const float wv = __int_as_float(p.y);
        const float4 v = *(const float4*)&vbar[(size_t)p.x * DD + d4];
        ax += wv * v.x; ay += wv * v.y; az += wv * v.z; aw += wv * v.w;
    }
    ax += __shfl_xor(ax, 16, 64);
    ay += __shfl_xor(ay, 16, 64);
    az += __shfl_xor(az, 16, 64);
    aw += __shfl_xor(aw, 16, 64);
    if (grp == 0) {
        float4 o = *(float4*)&out[(size_t)n * DD + d4];
        o.x += ax; o.y += ay; o.z += az; o.w += aw;
        *(float4*)&out[(size_t)n * DD + d4] = o;
    }
}

// ---------------------------------------------------------------------------
extern "C" void kernel_launch(void* const* d_in, const int* in_sizes, int n_in,
                              void* d_out, int out_size, void* d_ws, size_t ws_size,
                              hipStream_t stream)
{
    (void)in_sizes; (void)n_in; (void)out_size; (void)ws_size;
    const float* Xq = (const float*)d_in[0];
    const float* Xs = (const float*)d_in[1];
    const float* ew = (const float*)d_in[2];
    const float* Wq = (const float*)d_in[3];
    const float* bq = (const float*)d_in[4];
    const float* Wk = (const float*)d_in[5];
    const float* bk = (const float*)d_in[6];
    const float* Wv = (const float*)d_in[7];
    const float* bv = (const float*)d_in[8];
    const int* n_nodes = (const int*)d_in[9];
    const int* ei = (const int*)d_in[10];
    float* out = (float*)d_out;
    float* ws  = (float*)d_ws;

    // workspace layout (float units); q/k/v bf16
    const size_t SZ_QKV   = (size_t)NN * HD / 2;       // 4194304 each
    const size_t OFF_Q    = 0;
    const size_t OFF_K    = SZ_QKV;
    const size_t OFF_V    = SZ_QKV * 2;
    const size_t OFF_SS   = SZ_QKV * 3;                // 16 floats (zeroed)
    const size_t OFF_DEG  = OFF_SS + 16;               // NN ints (zeroed)
    const size_t OFF_CUR  = OFF_DEG + NN;              // NN ints (zeroed)
    const size_t OFF_WT   = OFF_CUR + NN;              // 3*65536 ushorts
    const size_t OFF_OFFS = OFF_WT + 3 * 65536 / 2;    // NN+1 (+pad)
    const size_t OFF_KV16 = OFF_OFFS + NN + 16;                       // 524288 bf16
    const size_t OFF_KSF  = OFF_KV16 + (size_t)BB * HH * 4096 / 2;    // 16384
    const size_t OFF_VSF  = OFF_KSF + (size_t)BB * HH * 64;           // 16384
    const size_t OFF_PAIR = OFF_VSF + (size_t)BB * HH * 64;           // 1048576
    const size_t OFF_VBAR = OFF_PAIR + 2 * (size_t)EE;                // 2097152
    // total ≈ 66 MB

    ushort* q16   = (ushort*)(ws + OFF_Q);
    ushort* k16   = (ushort*)(ws + OFF_K);
    ushort* v16   = (ushort*)(ws + OFF_V);
    float* sumsq  = ws + OFF_SS;
    int*   deg    = (int*)(ws + OFF_DEG);
    int*   cursor = (int*)(ws + OFF_CUR);
    ushort* WT    = (ushort*)(ws + OFF_WT);
    int*   offs   = (int*)(ws + OFF_OFFS);
    ushort* kv16  = (ushort*)(ws + OFF_KV16);
    float* ksum_f = ws + OFF_KSF;
    float* vsum_f = ws + OFF_VSF;
    int2*  pairb  = (int2*)(ws + OFF_PAIR);
    float* vbar   = ws + OFF_VBAR;

    // zero sumsq + deg + cursor (contiguous)
    hipMemsetAsync(sumsq, 0, (16 + 2 * NN) * sizeof(float), stream);
    prep_kernel<<<2816, 256, 0, stream>>>(Wq, Wk, Wv, WT, ei, deg);
    qkv_scan<<<1537, 256, 0, stream>>>(
        Xq, Xs, WT, bq, bk, bv, q16, k16, v16, sumsq, deg, offs);
    kv_vbar_bucket<<<3328, 256, 0, stream>>>(
        k16, v16, kv16, ksum_f, vsum_f, vbar, ei, ew, deg, offs, cursor, pairb);
    attn_mfma<<<dim3(MM / 64, BB), 256, 0, stream>>>(
        q16, kv16, ksum_f, vsum_f, sumsq, n_nodes, out);
    gcn_gather<<<(NN * 32) / 256, 256, 0, stream>>>(offs, pairb, vbar, out);
}

// Round 10
// 244.839 us; speedup vs baseline: 1.0119x; 1.0119x over previous
//
#include <hip/hip_runtime.h>
#include <hip/hip_bf16.h>

#define NN 32768   // nodes
#define BB 64      // graphs
#define MM 512     // nodes per graph
#define HH 4       // heads
#define DD 64      // head dim
#define INF 256    // input features
#define HD 256     // H*D
#define EE 524288  // edges

typedef unsigned short ushort;
typedef unsigned int uint;
typedef short s16x8 __attribute__((ext_vector_type(8)));
typedef ushort u16x8 __attribute__((ext_vector_type(8)));
typedef float f32x4 __attribute__((ext_vector_type(4)));

__device__ __forceinline__ ushort f2bf(float f) {
    uint u = __float_as_uint(f);
    return (ushort)((u + 0x7fffu + ((u >> 16) & 1u)) >> 16);
}
__device__ __forceinline__ float bf2f(ushort u) {
    return __uint_as_float((uint)u << 16);
}
__device__ __forceinline__ uint pkbf(float x, float y) {
    __hip_bfloat162 h = __float22bfloat162_rn(make_float2(x, y));
    return *(uint*)&h;
}

#define GLD16(gp, lp) __builtin_amdgcn_global_load_lds( \
    (const __attribute__((address_space(1))) void*)(gp), \
    (__attribute__((address_space(3))) void*)(lp), 16, 0, 0)

// ---------------------------------------------------------------------------
// K1: convert_w (blocks 0..767) ∪ deg histogram (blocks 768..2815).
// ---------------------------------------------------------------------------
__global__ __launch_bounds__(256) void prep_kernel(
    const float* __restrict__ Wq, const float* __restrict__ Wk,
    const float* __restrict__ Wv, ushort* __restrict__ WT,
    const int* __restrict__ ei, int* __restrict__ deg)
{
    const int bid = blockIdx.x;
    if (bid < 768) {
        const int id = bid * 256 + threadIdx.x;      // 3*65536
        const int mat = id >> 16, rem = id & 65535;
        const int n = rem >> 8, kk = rem & 255;
        const float* W = (mat == 0) ? Wq : (mat == 1) ? Wk : Wv;
        WT[id] = f2bf(W[kk * 256 + n]);              // WT[mat][n][kk]
    } else {
        const int e = (bid - 768) * 256 + threadIdx.x;   // EE total
        atomicAdd(&deg[ei[EE + e]], 1);
    }
}

// ---------------------------------------------------------------------------
// K2: qkv GEMM (blocks 1..1536) ∪ scan (block 0 — dispatched FIRST so its
// serial prefix-scan overlaps the GEMM blocks instead of forming a tail).
// A: f32 global->reg -> cvt_pk bf16 -> ds_write (2-buffer). B: bf16
// global_load_lds (3-buffer). All compute-needed vmcnt waits BEFORE the
// barrier (race-free cross-wave). LDS = exactly 40 KB -> 4 blocks/CU.
// ---------------------------------------------------------------------------
__global__ __launch_bounds__(256) void qkv_scan(
    const float* __restrict__ Xq, const float* __restrict__ Xs,
    const ushort* __restrict__ WT,
    const float* __restrict__ bq, const float* __restrict__ bk,
    const float* __restrict__ bv,
    ushort* __restrict__ qo, ushort* __restrict__ ko, ushort* __restrict__ vo,
    float* __restrict__ sumsq,
    const int* __restrict__ deg, int* __restrict__ offsets)
{
    __shared__ ushort As[2][128 * 32];
    __shared__ ushort Bs[3][128 * 32];
    // aliases with disjoint lifetimes (keep LDS at exactly 40 KB):
    int*   part = (int*)&As[0][0];     // scan path only (never runs GEMM)
    float* wred = (float*)&Bs[0][0];   // epilogue only (after last Bs[0] read)

    const int id = blockIdx.x;
    const int t = threadIdx.x;

    if (id == 0) {   // exclusive scan of deg -> offsets, int4-vectorized
        const int base = t * 128;
        int s = 0;
        for (int i = 0; i < 128; i += 4) {
            const int4 d = *(const int4*)&deg[base + i];
            s += d.x + d.y + d.z + d.w;
        }
        part[t] = s;
        __syncthreads();
        for (int off = 1; off < 256; off <<= 1) {
            int a = part[t];
            int b2 = (t >= off) ? part[t - off] : 0;
            __syncthreads();
            part[t] = a + b2;
            __syncthreads();
        }
        int run = (t == 0) ? 0 : part[t - 1];
        for (int i = 0; i < 128; i += 4) {
            const int4 d = *(const int4*)&deg[base + i];
            int4 o;
            o.x = run; run += d.x;
            o.y = run; run += d.y;
            o.z = run; run += d.z;
            o.w = run; run += d.w;
            *(int4*)&offsets[base + i] = o;
        }
        if (t == 255) offsets[NN] = run;
        return;
    }

    const int gid = id - 1;
    const int vv = (gid & 7) * 192 + (gid >> 3);   // XCD-contiguous row-groups
    const int rt = vv / 6, ct = vv % 6;
    const int wsel = ct >> 1;                    // 0:q 1:k 2:v
    const float* A    = (wsel == 0) ? Xq : Xs;
    const ushort* W   = WT + (size_t)wsel * 65536;
    const float* bias = (wsel == 0) ? bq : (wsel == 1) ? bk : bv;
    ushort* C         = (wsel == 0) ? qo : (wsel == 1) ? ko : vo;
    const int row0 = rt * 128;
    const int col0 = (ct & 1) * 128;

    const int l = t & 63, w = t >> 6;
    const int fr = l & 15, q4 = l >> 4;
    const int wr = (w & 1) * 64, wc = (w >> 1) * 64;

    // staging geometry: per wave, 64 lanes; row = w*16 + l/4, K-chunk (l&3)*8
    const int srow = (w << 4) + (l >> 2);        // 0..63 within 64-row half
    const int scol = (l & 3) << 3;               // 0,8,16,24 (elems)
    const float*  ga = &A[(size_t)(row0 + srow) * INF + scol];
    const ushort* gb = &W[(size_t)(col0 + srow) * INF + scol];
    const int lbase = (w << 9);                  // wave-uniform ushort offset

    f32x4 acc[4][4] = {};
    float4 a00, a01, a10, a11;                   // A f32 staging regs

#define QKV_ALOAD(k0) { \
    const float* p0 = ga + (k0); \
    const float* p1 = ga + (k0) + 64 * INF; \
    a00 = *(const float4*)(p0);     a01 = *(const float4*)(p0 + 4); \
    a10 = *(const float4*)(p1);     a11 = *(const float4*)(p1 + 4); }

#define QKV_AWRITE(abuf) { \
    union { u16x8 v; uint u[4]; } c0, c1; \
    c0.u[0] = pkbf(a00.x, a00.y); c0.u[1] = pkbf(a00.z, a00.w); \
    c0.u[2] = pkbf(a01.x, a01.y); c0.u[3] = pkbf(a01.z, a01.w); \
    c1.u[0] = pkbf(a10.x, a10.y); c1.u[1] = pkbf(a10.z, a10.w); \
    c1.u[2] = pkbf(a11.x, a11.y); c1.u[3] = pkbf(a11.z, a11.w); \
    *(u16x8*)&As[abuf][srow * 32 + scol]        = c0.v; \
    *(u16x8*)&As[abuf][2048 + srow * 32 + scol] = c1.v; }

#define QKV_BSTAGE(bbuf, k0) \
    GLD16(gb + (k0),            &Bs[bbuf][lbase]); \
    GLD16(gb + (k0) + 64 * INF, &Bs[bbuf][2048 + lbase]);

#define QKV_COMPUTE(abuf, bbuf) { \
    const int kg = q4 * 8; \
    s16x8 af[4], bfr[4]; \
    _Pragma("unroll") \
    for (int i = 0; i < 4; ++i) \
        af[i] = *(const s16x8*)&As[abuf][(wr + i * 16 + fr) * 32 + kg]; \
    _Pragma("unroll") \
    for (int j = 0; j < 4; ++j) \
        bfr[j] = *(const s16x8*)&Bs[bbuf][(wc + j * 16 + fr) * 32 + kg]; \
    _Pragma("unroll") \
    for (int i = 0; i < 4; ++i) \
    _Pragma("unroll") \
        for (int j = 0; j < 4; ++j) \
            acc[i][j] = __builtin_amdgcn_mfma_f32_16x16x32_bf16( \
                af[i], bfr[j], acc[i][j], 0, 0, 0); }

#define WAITN(n) asm volatile("s_waitcnt vmcnt(" #n ")" ::: "memory")
#define LGKM0   asm volatile("s_waitcnt lgkmcnt(0)" ::: "memory")
#define BAR     __builtin_amdgcn_s_barrier()

    // prologue: A0(4) + B0(2) + B1(2) in flight = 8 outstanding
    QKV_ALOAD(0)
    QKV_BSTAGE(0, 0)
    QKV_BSTAGE(1, 32)

    // it0: [A0,B0,B1]=8 -> wait(2) completes A0+B0 (pre-barrier!)
    WAITN(2); QKV_AWRITE(0) LGKM0; BAR;
    QKV_ALOAD(32)  QKV_BSTAGE(2, 64)   QKV_COMPUTE(0, 0)
    // it1: [B1,A1,B2]=8 -> wait(2) completes B1+A1
    WAITN(2); QKV_AWRITE(1) LGKM0; BAR;
    QKV_ALOAD(64)  QKV_BSTAGE(0, 96)   QKV_COMPUTE(1, 1)
    // it2: [B2,A2,B0]=8 -> wait(2) completes B2+A2
    WAITN(2); QKV_AWRITE(0) LGKM0; BAR;
    QKV_ALOAD(96)  QKV_BSTAGE(1, 128)  QKV_COMPUTE(0, 2)
    // it3: [B0,A3,B1]=8 -> wait(2) completes B0+A3
    WAITN(2); QKV_AWRITE(1) LGKM0; BAR;
    QKV_ALOAD(128) QKV_BSTAGE(2, 160)  QKV_COMPUTE(1, 0)
    // it4: [B1,A4,B2]=8 -> wait(2) completes B1+A4
    WAITN(2); QKV_AWRITE(0) LGKM0; BAR;
    QKV_ALOAD(160) QKV_BSTAGE(0, 192)  QKV_COMPUTE(0, 1)
    // it5: [B2,A5,B0]=8 -> wait(2) completes B2+A5
    WAITN(2); QKV_AWRITE(1) LGKM0; BAR;
    QKV_ALOAD(192) QKV_BSTAGE(1, 224)  QKV_COMPUTE(1, 2)
    // it6: [B0,A6,B1]=8 -> wait(2) completes B0+A6
    WAITN(2); QKV_AWRITE(0) LGKM0; BAR;
    QKV_ALOAD(224)                     QKV_COMPUTE(0, 0)
    // it7: [B1,A7]=6 -> wait(0) drains
    WAITN(0); QKV_AWRITE(1) LGKM0; BAR;
    QKV_COMPUTE(1, 1)

    float loc = 0.f;
#pragma unroll
    for (int j = 0; j < 4; ++j) {
        const int colg = col0 + wc + j * 16 + fr;
        const float bj = bias[colg];
#pragma unroll
        for (int i = 0; i < 4; ++i) {
            const int rowg = row0 + wr + i * 16 + q4 * 4;
            const float cv0 = acc[i][j][0] + bj;
            const float cv1 = acc[i][j][1] + bj;
            const float cv2 = acc[i][j][2] + bj;
            const float cv3 = acc[i][j][3] + bj;
            loc += cv0 * cv0 + cv1 * cv1 + cv2 * cv2 + cv3 * cv3;
            const uint p01 = pkbf(cv0, cv1);
            const uint p23 = pkbf(cv2, cv3);
            C[(size_t)(rowg + 0) * HD + colg] = (ushort)p01;
            C[(size_t)(rowg + 1) * HD + colg] = (ushort)(p01 >> 16);
            C[(size_t)(rowg + 2) * HD + colg] = (ushort)p23;
            C[(size_t)(rowg + 3) * HD + colg] = (ushort)(p23 >> 16);
        }
    }
    if (wsel < 2) {
#pragma unroll
        for (int off = 32; off > 0; off >>= 1) loc += __shfl_down(loc, off, 64);
        __syncthreads();               // all As/Bs reads done before wred alias
        if (l == 0) wred[w] = loc;
        __syncthreads();
        if (t == 0) atomicAdd(&sumsq[wsel], wred[0] + wred[1] + wred[2] + wred[3]);
    }
}

// ---------------------------------------------------------------------------
// K3: kv full-pass MFMA (blocks 0..255: one (b,h), 8 chunks of 64 rows,
// in-register accumulation; 18.4 KB LDS) ∪ vbar (blocks 256..1279, 16B
// loads) ∪ bucket (blocks 1280..3327).
// ---------------------------------------------------------------------------
#define KVP 72
__global__ __launch_bounds__(256) void kv_vbar_bucket(
    const ushort* __restrict__ k16, const ushort* __restrict__ v16,
    ushort* __restrict__ kv16, float* __restrict__ ksum_f, float* __restrict__ vsum_f,
    float* __restrict__ vbar,
    const int* __restrict__ ei, const float* __restrict__ ew,
    const int* __restrict__ deg, const int* __restrict__ offsets,
    int* __restrict__ cursor, int2* __restrict__ pairbuf)
{
    __shared__ ushort kT[64 * KVP];
    __shared__ ushort vT[64 * KVP];
    const int bid = blockIdx.x;
    const int t = threadIdx.x;

    if (bid >= 1280) {   // bucket: CSR fill, packed int2 {row, val}
        const int e = (bid - 1280) * 256 + t;
        const int row = ei[e], col = ei[EE + e];
        const long long prod = (long long)deg[row] * (long long)deg[col];
        float val = 0.f;
        if (prod > 0) val = ew[e] * __frsqrt_rn((float)prod);
        const int pos = atomicAdd(&cursor[col], 1);
        pairbuf[offsets[col] + pos] = make_int2(row, __float_as_int(val));
        return;
    }
    if (bid >= 256) {    // vbar: mean over heads, 8 d/thread, 16B loads
        const int idx = (bid - 256) * 256 + t;   // NN*8 total
        const int n = idx >> 3, d0 = (idx & 7) * 8;
        const ushort* vr = &v16[(size_t)n * HD + d0];
        u16x8 v0 = *(const u16x8*)(vr);
        u16x8 v1 = *(const u16x8*)(vr + 64);
        u16x8 v2 = *(const u16x8*)(vr + 128);
        u16x8 v3 = *(const u16x8*)(vr + 192);
        float o[8];
#pragma unroll
        for (int j = 0; j < 8; ++j)
            o[j] = 0.25f * (bf2f(v0[j]) + bf2f(v1[j]) + bf2f(v2[j]) + bf2f(v3[j]));
        float* vb = &vbar[(size_t)n * DD + d0];
        *(float4*)(vb)     = make_float4(o[0], o[1], o[2], o[3]);
        *(float4*)(vb + 4) = make_float4(o[4], o[5], o[6], o[7]);
        return;
    }

    // ---- kv MFMA: one (b,h), all 512 rows in 8 chunks of 64 ----
    const int h = bid & 3, b = bid >> 2;
    const int l = t & 63, w = t >> 6;
    const size_t base = (size_t)b * MM * HD + (size_t)h * DD;

    const int fr = l & 15, q4 = l >> 4, kg = q4 * 8;
    const int wr2 = (w & 1) * 32, wc2 = (w >> 1) * 32;
    s16x8 ones;
#pragma unroll
    for (int i = 0; i < 8; ++i) ones[i] = (short)0x3F80;

    f32x4 acc[2][2] = {};
    f32x4 aks[2] = {};
    f32x4 avs[2] = {};

    // staging decomposition (constant across chunks)
    const int mat = t >> 7;
    const int rem = t & 127;
    const int dq  = rem >> 5;          // 0..3
    const int u   = rem & 31;          // row-pair index
    const int r0  = 2 * u;             // rows r0, r0+1 within chunk
    const int d0  = dq * 16;
    const ushort* src = mat ? v16 : k16;
    ushort* dst = mat ? vT : kT;

    for (int chunk = 0; chunk < 8; ++chunk) {
        const int m0 = chunk * 64;
        {   // transpose-stage 64 rows x 64 d (2 rows/thread, packed uint)
            const ushort* p0 = &src[base + (size_t)(m0 + r0) * HD + d0];
            const ushort* p1 = p0 + HD;
            u16x8 ra0 = *(const u16x8*)(p0);
            u16x8 ra1 = *(const u16x8*)(p0 + 8);
            u16x8 rb0 = *(const u16x8*)(p1);
            u16x8 rb1 = *(const u16x8*)(p1 + 8);
#pragma unroll
            for (int jj = 0; jj < 8; ++jj) {
                uint pk = (uint)ra0[jj] | ((uint)rb0[jj] << 16);
                *(uint*)&dst[(d0 + jj) * KVP + r0] = pk;
            }
#pragma unroll
            for (int jj = 0; jj < 8; ++jj) {
                uint pk = (uint)ra1[jj] | ((uint)rb1[jj] << 16);
                *(uint*)&dst[(d0 + 8 + jj) * KVP + r0] = pk;
            }
        }
        __syncthreads();

#pragma unroll
        for (int s = 0; s < 2; ++s) {
            const int mo = s * 32 + kg;
            s16x8 af[2], bf[2];
            af[0] = *(const s16x8*)&kT[(wr2 + fr) * KVP + mo];
            af[1] = *(const s16x8*)&kT[(wr2 + 16 + fr) * KVP + mo];
            bf[0] = *(const s16x8*)&vT[(wc2 + fr) * KVP + mo];
            bf[1] = *(const s16x8*)&vT[(wc2 + 16 + fr) * KVP + mo];
#pragma unroll
            for (int il = 0; il < 2; ++il)
#pragma unroll
                for (int jl = 0; jl < 2; ++jl)
                    acc[il][jl] = __builtin_amdgcn_mfma_f32_16x16x32_bf16(
                        af[il], bf[jl], acc[il][jl], 0, 0, 0);
#pragma unroll
            for (int il = 0; il < 2; ++il)
                aks[il] = __builtin_amdgcn_mfma_f32_16x16x32_bf16(
                    af[il], ones, aks[il], 0, 0, 0);
#pragma unroll
            for (int jl = 0; jl < 2; ++jl)
                avs[jl] = __builtin_amdgcn_mfma_f32_16x16x32_bf16(
                    ones, bf[jl], avs[jl], 0, 0, 0);
        }
        __syncthreads();   // protect LDS overwrite by next chunk
    }

    // epilogue: kv16 bf16 direct, transposed [dv][dk]
    ushort* kvb = &kv16[((size_t)b * HH + h) * 4096];
#pragma unroll
    for (int jl = 0; jl < 2; ++jl) {
        const int dv = wc2 + 16 * jl + fr;
#pragma unroll
        for (int il = 0; il < 2; ++il) {
            const int dk = wr2 + 16 * il + q4 * 4;
            uint2 pk = make_uint2(pkbf(acc[il][jl][0], acc[il][jl][1]),
                                  pkbf(acc[il][jl][2], acc[il][jl][3]));
            *(uint2*)&kvb[(size_t)dv * 64 + dk] = pk;
        }
    }
    float* ksb = &ksum_f[((size_t)b * HH + h) * 64];
    float* vsb = &vsum_f[((size_t)b * HH + h) * 64];
    if (wc2 == 0 && fr == 0) {
#pragma unroll
        for (int il = 0; il < 2; ++il)
#pragma unroll
            for (int m = 0; m < 4; ++m)
                ksb[wr2 + 16 * il + q4 * 4 + m] = aks[il][m];
    }
    if (wr2 == 0 && l < 16) {
        vsb[wc2 + l]      = avs[0][0];
        vsb[wc2 + 16 + l] = avs[1][0];
    }
}

// ---------------------------------------------------------------------------
// K5: attn via MFMA. All 4 heads' KV + sums staged once; all 256
// denominators in one phase; head loop pure MFMA+epilogue, 2 barriers.
// ---------------------------------------------------------------------------
#define AKP 72
__global__ __launch_bounds__(256) void attn_mfma(
    const ushort* __restrict__ q16, const ushort* __restrict__ kv16,
    const float* __restrict__ ksum_f, const float* __restrict__ vsum_f,
    const float* __restrict__ sumsq,
    const int* __restrict__ n_nodes, float* __restrict__ out)
{
    const int b = blockIdx.y;
    const int m0 = blockIdx.x * 64;
    const int t = threadIdx.x;
    const int l = t & 63, w = t >> 6;
    const int fr = l & 15, q4 = l >> 4;
    const int wn = (w & 1) * 32, wd = (w >> 1) * 32;

    __shared__ ushort kvbf[HH][64 * AKP];
    __shared__ float ksum_l[HH][64], vsum_l[HH][64], denom_l[HH][64];

    const float nn = (float)n_nodes[b];
    const float inv = 1.0f / (sqrtf(sumsq[0]) * sqrtf(sumsq[1]));

    {   // stage all heads: bf16 KV [dv][dk] + ksum/vsum
        const int dv = t >> 2, dk0 = (t & 3) * 16;
#pragma unroll
        for (int h = 0; h < HH; ++h) {
            const ushort* kvg = &kv16[((size_t)(b * HH + h)) * 4096 + dv * 64 + dk0];
            *(uint4*)&kvbf[h][dv * AKP + dk0]     = *(const uint4*)kvg;
            *(uint4*)&kvbf[h][dv * AKP + dk0 + 8] = *(const uint4*)(kvg + 8);
        }
        const int hh = t >> 6, dd = t & 63;
        ksum_l[hh][dd] = ksum_f[((size_t)(b * HH + hh)) * 64 + dd];
        vsum_l[hh][dd] = vsum_f[((size_t)(b * HH + hh)) * 64 + dd];
    }
    __syncthreads();

    {   // denominators, all heads at once: thread = (row r, head hh)
        const int r = t & 63, hh = t >> 6;
        const ushort* qr = &q16[((size_t)(b * MM + m0 + r)) * HD + hh * DD];
        float dsum = 0.f;
#pragma unroll
        for (int c = 0; c < 8; ++c) {
            u16x8 qv = *(const u16x8*)(qr + 8 * c);
#pragma unroll
            for (int j2 = 0; j2 < 8; ++j2)
                dsum += bf2f(qv[j2]) * ksum_l[hh][8 * c + j2];
        }
        denom_l[hh][r] = nn + inv * dsum;
    }
    __syncthreads();

    f32x4 acco[2][2] = {};
#pragma unroll
    for (int h = 0; h < HH; ++h) {
        f32x4 pacc[2][2] = {};
#pragma unroll
        for (int kx = 0; kx < 2; ++kx) {
            const int k0 = kx * 32;
            s16x8 af[2], bfr[2];
#pragma unroll
            for (int il = 0; il < 2; ++il)
                af[il] = *(const s16x8*)&q16[
                    ((size_t)(b * MM + m0 + wn + 16 * il + fr)) * HD + h * DD + k0 + q4 * 8];
#pragma unroll
            for (int jl = 0; jl < 2; ++jl)
                bfr[jl] = *(const s16x8*)&kvbf[h][(wd + 16 * jl + fr) * AKP + k0 + q4 * 8];
#pragma unroll
            for (int il = 0; il < 2; ++il)
#pragma unroll
                for (int jl = 0; jl < 2; ++jl)
                    pacc[il][jl] = __builtin_amdgcn_mfma_f32_16x16x32_bf16(
                        af[il], bfr[jl], pacc[il][jl], 0, 0, 0);
        }
#pragma unroll
        for (int il = 0; il < 2; ++il)
#pragma unroll
            for (int m = 0; m < 4; ++m) {
                const float rden = 0.25f / denom_l[h][wn + 16 * il + q4 * 4 + m];
#pragma unroll
                for (int jl = 0; jl < 2; ++jl) {
                    const int d = wd + 16 * jl + fr;
                    acco[il][jl][m] += (inv * pacc[il][jl][m] + vsum_l[h][d]) * rden;
                }
            }
    }

#pragma unroll
    for (int il = 0; il < 2; ++il)
#pragma unroll
        for (int m = 0; m < 4; ++m) {
            const size_t node = (size_t)b * MM + m0 + wn + 16 * il + q4 * 4 + m;
#pragma unroll
            for (int jl = 0; jl < 2; ++jl)
                out[node * DD + wd + 16 * jl + fr] = acco[il][jl][m];
        }
}

// ---------------------------------------------------------------------------
// K6: GCN gather, 32 threads/node (2 groups of 16 split even/odd edges,
// combine via shfl_xor 16).
// ---------------------------------------------------------------------------
__global__ __launch_bounds__(256) void gcn_gather(
    const int* __restrict__ offsets, const int2* __restrict__ pairbuf,
    const float* __restrict__ vbar, float* __restrict__ out)
{
    const int t = blockIdx.x * 256 + threadIdx.x;   // NN*32 threads
    const int n = t >> 5;
    const int g = t & 31;
    const int d4 = (g & 15) << 2;
    const int grp = g >> 4;
    const int s = offsets[n], e = offsets[n + 1];
    float ax = 0.f, ay = 0.f, az = 0.f, aw = 0.f;
    int i = s + grp;
    for (; i + 2 < e; i += 4) {   // two edges (stride-2 within group)
        const int2 p0 = pairbuf[i], p1 = pairbuf[i + 2];
        const float w0 = __int_as_float(p0.y), w1 = __int_as_float(p1.y);
        const float4 v0 = *(const float4*)&vbar[(size_t)p0.x * DD + d4];
        const float4 v1 = *(const float4*)&vbar[(size_t)p1.x * DD + d4];
        ax += w0 * v0.x + w1 * v1.x;
        ay += w0 * v0.y + w1 * v1.y;
        az += w0 * v0.z + w1 * v1.z;
        aw += w0 * v0.w + w1 * v1.w;
    }
    if (i < e) {
        const int2 p = pairbuf[i];
        const float wv = __int_as_float(p.y);
        const float4 v = *(const float4*)&vbar[(size_t)p.x * DD + d4];
        ax += wv * v.x; ay += wv * v.y; az += wv * v.z; aw += wv * v.w;
    }
    ax += __shfl_xor(ax, 16, 64);
    ay += __shfl_xor(ay, 16, 64);
    az += __shfl_xor(az, 16, 64);
    aw += __shfl_xor(aw, 16, 64);
    if (grp == 0) {
        float4 o = *(float4*)&out[(size_t)n * DD + d4];
        o.x += ax; o.y += ay; o.z += az; o.w += aw;
        *(float4*)&out[(size_t)n * DD + d4] = o;
    }
}

// ---------------------------------------------------------------------------
extern "C" void kernel_launch(void* const* d_in, const int* in_sizes, int n_in,
                              void* d_out, int out_size, void* d_ws, size_t ws_size,
                              hipStream_t stream)
{
    (void)in_sizes; (void)n_in; (void)out_size; (void)ws_size;
    const float* Xq = (const float*)d_in[0];
    const float* Xs = (const float*)d_in[1];
    const float* ew = (const float*)d_in[2];
    const float* Wq = (const float*)d_in[3];
    const float* bq = (const float*)d_in[4];
    const float* Wk = (const float*)d_in[5];
    const float* bk = (const float*)d_in[6];
    const float* Wv = (const float*)d_in[7];
    const float* bv = (const float*)d_in[8];
    const int* n_nodes = (const int*)d_in[9];
    const int* ei = (const int*)d_in[10];
    float* out = (float*)d_out;
    float* ws  = (float*)d_ws;

    // workspace layout (float units); q/k/v bf16
    const size_t SZ_QKV   = (size_t)NN * HD / 2;       // 4194304 each
    const size_t OFF_Q    = 0;
    const size_t OFF_K    = SZ_QKV;
    const size_t OFF_V    = SZ_QKV * 2;
    const size_t OFF_SS   = SZ_QKV * 3;                // 16 floats (zeroed)
    const size_t OFF_DEG  = OFF_SS + 16;               // NN ints (zeroed)
    const size_t OFF_CUR  = OFF_DEG + NN;              // NN ints (zeroed)
    const size_t OFF_WT   = OFF_CUR + NN;              // 3*65536 ushorts
    const size_t OFF_OFFS = OFF_WT + 3 * 65536 / 2;    // NN+1 (+pad)
    const size_t OFF_KV16 = OFF_OFFS + NN + 16;                       // 524288 bf16
    const size_t OFF_KSF  = OFF_KV16 + (size_t)BB * HH * 4096 / 2;    // 16384
    const size_t OFF_VSF  = OFF_KSF + (size_t)BB * HH * 64;           // 16384
    const size_t OFF_PAIR = OFF_VSF + (size_t)BB * HH * 64;           // 1048576
    const size_t OFF_VBAR = OFF_PAIR + 2 * (size_t)EE;                // 2097152
    // total ≈ 66 MB

    ushort* q16   = (ushort*)(ws + OFF_Q);
    ushort* k16   = (ushort*)(ws + OFF_K);
    ushort* v16   = (ushort*)(ws + OFF_V);
    float* sumsq  = ws + OFF_SS;
    int*   deg    = (int*)(ws + OFF_DEG);
    int*   cursor = (int*)(ws + OFF_CUR);
    ushort* WT    = (ushort*)(ws + OFF_WT);
    int*   offs   = (int*)(ws + OFF_OFFS);
    ushort* kv16  = (ushort*)(ws + OFF_KV16);
    float* ksum_f = ws + OFF_KSF;
    float* vsum_f = ws + OFF_VSF;
    int2*  pairb  = (int2*)(ws + OFF_PAIR);
    float* vbar   = ws + OFF_VBAR;

    // zero sumsq + deg + cursor (contiguous)
    hipMemsetAsync(sumsq, 0, (16 + 2 * NN) * sizeof(float), stream);
    prep_kernel<<<2816, 256, 0, stream>>>(Wq, Wk, Wv, WT, ei, deg);
    qkv_scan<<<1537, 256, 0, stream>>>(
        Xq, Xs, WT, bq, bk, bv, q16, k16, v16, sumsq, deg, offs);
    kv_vbar_bucket<<<3328, 256, 0, stream>>>(
        k16, v16, kv16, ksum_f, vsum_f, vbar, ei, ew, deg, offs, cursor, pairb);
    attn_mfma<<<dim3(MM / 64, BB), 256, 0, stream>>>(
        q16, kv16, ksum_f, vsum_f, sumsq, n_nodes, out);
    gcn_gather<<<(NN * 32) / 256, 256, 0, stream>>>(offs, pairb, vbar, out);
}

// Round 11
// 239.480 us; speedup vs baseline: 1.0346x; 1.0224x over previous
//
#include <hip/hip_runtime.h>
#include <hip/hip_bf16.h>

#define NN 32768   // nodes
#define BB 64      // graphs
#define MM 512     // nodes per graph
#define HH 4       // heads
#define DD 64      // head dim
#define INF 256    // input features
#define HD 256     // H*D
#define EE 524288  // edges

typedef unsigned short ushort;
typedef unsigned int uint;
typedef short s16x8 __attribute__((ext_vector_type(8)));
typedef ushort u16x8 __attribute__((ext_vector_type(8)));
typedef float f32x4 __attribute__((ext_vector_type(4)));

__device__ __forceinline__ ushort f2bf(float f) {
    uint u = __float_as_uint(f);
    return (ushort)((u + 0x7fffu + ((u >> 16) & 1u)) >> 16);
}
__device__ __forceinline__ float bf2f(ushort u) {
    return __uint_as_float((uint)u << 16);
}
__device__ __forceinline__ uint pkbf(float x, float y) {
    __hip_bfloat162 h = __float22bfloat162_rn(make_float2(x, y));
    return *(uint*)&h;
}

#define GLD16(gp, lp) __builtin_amdgcn_global_load_lds( \
    (const __attribute__((address_space(1))) void*)(gp), \
    (__attribute__((address_space(3))) void*)(lp), 16, 0, 0)

// ---------------------------------------------------------------------------
// K1: convert_w (blocks 0..767) ∪ deg histogram (blocks 768..2815).
// ---------------------------------------------------------------------------
__global__ __launch_bounds__(256) void prep_kernel(
    const float* __restrict__ Wq, const float* __restrict__ Wk,
    const float* __restrict__ Wv, ushort* __restrict__ WT,
    const int* __restrict__ ei, int* __restrict__ deg)
{
    const int bid = blockIdx.x;
    if (bid < 768) {
        const int id = bid * 256 + threadIdx.x;      // 3*65536
        const int mat = id >> 16, rem = id & 65535;
        const int n = rem >> 8, kk = rem & 255;
        const float* W = (mat == 0) ? Wq : (mat == 1) ? Wk : Wv;
        WT[id] = f2bf(W[kk * 256 + n]);              // WT[mat][n][kk]
    } else {
        const int e = (bid - 768) * 256 + threadIdx.x;   // EE total
        atomicAdd(&deg[ei[EE + e]], 1);
    }
}

// ---------------------------------------------------------------------------
// K2: qkv GEMM (blocks 1..1536) ∪ scan (block 0, dispatched first).
// A: f32 global->reg with TWO register buffers (2 barrier-periods of
// flight, matching B) -> cvt_pk bf16 -> ds_write (2-buffer LDS).
// B: bf16 global_load_lds (3-buffer). Steady state: 12 loads outstanding,
// WAITN(6) at iter top completes A(cur)+B(cur) BEFORE the barrier
// (cross-wave-safe). launch_bounds(256,4) pins VGPR <= 128 so the
// LDS-limited 4 blocks/CU occupancy is preserved.
// ---------------------------------------------------------------------------
__global__ __launch_bounds__(256, 4) void qkv_scan(
    const float* __restrict__ Xq, const float* __restrict__ Xs,
    const ushort* __restrict__ WT,
    const float* __restrict__ bq, const float* __restrict__ bk,
    const float* __restrict__ bv,
    ushort* __restrict__ qo, ushort* __restrict__ ko, ushort* __restrict__ vo,
    float* __restrict__ sumsq,
    const int* __restrict__ deg, int* __restrict__ offsets)
{
    __shared__ ushort As[2][128 * 32];
    __shared__ ushort Bs[3][128 * 32];
    // aliases with disjoint lifetimes (keep LDS at exactly 40 KB):
    int*   part = (int*)&As[0][0];     // scan path only (never runs GEMM)
    float* wred = (float*)&Bs[0][0];   // epilogue only (after last Bs[0] read)

    const int id = blockIdx.x;
    const int t = threadIdx.x;

    if (id == 0) {   // exclusive scan of deg -> offsets, int4-vectorized
        const int base = t * 128;
        int s = 0;
        for (int i = 0; i < 128; i += 4) {
            const int4 d = *(const int4*)&deg[base + i];
            s += d.x + d.y + d.z + d.w;
        }
        part[t] = s;
        __syncthreads();
        for (int off = 1; off < 256; off <<= 1) {
            int a = part[t];
            int b2 = (t >= off) ? part[t - off] : 0;
            __syncthreads();
            part[t] = a + b2;
            __syncthreads();
        }
        int run = (t == 0) ? 0 : part[t - 1];
        for (int i = 0; i < 128; i += 4) {
            const int4 d = *(const int4*)&deg[base + i];
            int4 o;
            o.x = run; run += d.x;
            o.y = run; run += d.y;
            o.z = run; run += d.z;
            o.w = run; run += d.w;
            *(int4*)&offsets[base + i] = o;
        }
        if (t == 255) offsets[NN] = run;
        return;
    }

    const int gid = id - 1;
    const int vv = (gid & 7) * 192 + (gid >> 3);   // XCD-contiguous row-groups
    const int rt = vv / 6, ct = vv % 6;
    const int wsel = ct >> 1;                    // 0:q 1:k 2:v
    const float* A    = (wsel == 0) ? Xq : Xs;
    const ushort* W   = WT + (size_t)wsel * 65536;
    const float* bias = (wsel == 0) ? bq : (wsel == 1) ? bk : bv;
    ushort* C         = (wsel == 0) ? qo : (wsel == 1) ? ko : vo;
    const int row0 = rt * 128;
    const int col0 = (ct & 1) * 128;

    const int l = t & 63, w = t >> 6;
    const int fr = l & 15, q4 = l >> 4;
    const int wr = (w & 1) * 64, wc = (w >> 1) * 64;

    // staging geometry: per wave, 64 lanes; row = w*16 + l/4, K-chunk (l&3)*8
    const int srow = (w << 4) + (l >> 2);        // 0..63 within 64-row half
    const int scol = (l & 3) << 3;               // 0,8,16,24 (elems)
    const float*  ga = &A[(size_t)(row0 + srow) * INF + scol];
    const ushort* gb = &W[(size_t)(col0 + srow) * INF + scol];
    const int lbase = (w << 9);                  // wave-uniform ushort offset

    f32x4 acc[4][4] = {};
    float4 aA0, aA1, aA2, aA3;                   // A staging regs, set A
    float4 aB0, aB1, aB2, aB3;                   // A staging regs, set B

#define QKV_ALOADA(k0) { \
    const float* p0 = ga + (k0); \
    const float* p1 = ga + (k0) + 64 * INF; \
    aA0 = *(const float4*)(p0);     aA1 = *(const float4*)(p0 + 4); \
    aA2 = *(const float4*)(p1);     aA3 = *(const float4*)(p1 + 4); }

#define QKV_ALOADB(k0) { \
    const float* p0 = ga + (k0); \
    const float* p1 = ga + (k0) + 64 * INF; \
    aB0 = *(const float4*)(p0);     aB1 = *(const float4*)(p0 + 4); \
    aB2 = *(const float4*)(p1);     aB3 = *(const float4*)(p1 + 4); }

#define QKV_AWRITEA(abuf) { \
    union { u16x8 v; uint u[4]; } c0, c1; \
    c0.u[0] = pkbf(aA0.x, aA0.y); c0.u[1] = pkbf(aA0.z, aA0.w); \
    c0.u[2] = pkbf(aA1.x, aA1.y); c0.u[3] = pkbf(aA1.z, aA1.w); \
    c1.u[0] = pkbf(aA2.x, aA2.y); c1.u[1] = pkbf(aA2.z, aA2.w); \
    c1.u[2] = pkbf(aA3.x, aA3.y); c1.u[3] = pkbf(aA3.z, aA3.w); \
    *(u16x8*)&As[abuf][srow * 32 + scol]        = c0.v; \
    *(u16x8*)&As[abuf][2048 + srow * 32 + scol] = c1.v; }

#define QKV_AWRITEB(abuf) { \
    union { u16x8 v; uint u[4]; } c0, c1; \
    c0.u[0] = pkbf(aB0.x, aB0.y); c0.u[1] = pkbf(aB0.z, aB0.w); \
    c0.u[2] = pkbf(aB1.x, aB1.y); c0.u[3] = pkbf(aB1.z, aB1.w); \
    c1.u[0] = pkbf(aB2.x, aB2.y); c1.u[1] = pkbf(aB2.z, aB2.w); \
    c1.u[2] = pkbf(aB3.x, aB3.y); c1.u[3] = pkbf(aB3.z, aB3.w); \
    *(u16x8*)&As[abuf][srow * 32 + scol]        = c0.v; \
    *(u16x8*)&As[abuf][2048 + srow * 32 + scol] = c1.v; }

#define QKV_BSTAGE(bbuf, k0) \
    GLD16(gb + (k0),            &Bs[bbuf][lbase]); \
    GLD16(gb + (k0) + 64 * INF, &Bs[bbuf][2048 + lbase]);

#define QKV_COMPUTE(abuf, bbuf) { \
    const int kg = q4 * 8; \
    s16x8 af[4], bfr[4]; \
    _Pragma("unroll") \
    for (int i = 0; i < 4; ++i) \
        af[i] = *(const s16x8*)&As[abuf][(wr + i * 16 + fr) * 32 + kg]; \
    _Pragma("unroll") \
    for (int j = 0; j < 4; ++j) \
        bfr[j] = *(const s16x8*)&Bs[bbuf][(wc + j * 16 + fr) * 32 + kg]; \
    _Pragma("unroll") \
    for (int i = 0; i < 4; ++i) \
    _Pragma("unroll") \
        for (int j = 0; j < 4; ++j) \
            acc[i][j] = __builtin_amdgcn_mfma_f32_16x16x32_bf16( \
                af[i], bfr[j], acc[i][j], 0, 0, 0); }

#define WAITN(n) asm volatile("s_waitcnt vmcnt(" #n ")" ::: "memory")
#define LGKM0   asm volatile("s_waitcnt lgkmcnt(0)" ::: "memory")
#define BAR     __builtin_amdgcn_s_barrier()

    // prologue (issue order A-then-B, twice):
    // outstanding: [A0(4), B0(2), A32(4), B32(2)] = 12
    QKV_ALOADA(0)
    QKV_BSTAGE(0, 0)
    QKV_ALOADB(32)
    QKV_BSTAGE(1, 32)

    // it0: wait(6) completes A0+B0 (pre-barrier)
    WAITN(6); QKV_AWRITEA(0) LGKM0; BAR;
    QKV_ALOADA(64)  QKV_BSTAGE(2, 64)   QKV_COMPUTE(0, 0)
    // it1: [A32,B32,A64,B64]=12 -> wait(6) completes A32+B32
    WAITN(6); QKV_AWRITEB(1) LGKM0; BAR;
    QKV_ALOADB(96)  QKV_BSTAGE(0, 96)   QKV_COMPUTE(1, 1)
    // it2: completes A64+B64
    WAITN(6); QKV_AWRITEA(0) LGKM0; BAR;
    QKV_ALOADA(128) QKV_BSTAGE(1, 128)  QKV_COMPUTE(0, 2)
    // it3: completes A96+B96
    WAITN(6); QKV_AWRITEB(1) LGKM0; BAR;
    QKV_ALOADB(160) QKV_BSTAGE(2, 160)  QKV_COMPUTE(1, 0)
    // it4: completes A128+B128
    WAITN(6); QKV_AWRITEA(0) LGKM0; BAR;
    QKV_ALOADA(192) QKV_BSTAGE(0, 192)  QKV_COMPUTE(0, 1)
    // it5: completes A160+B160
    WAITN(6); QKV_AWRITEB(1) LGKM0; BAR;
    QKV_ALOADB(224) QKV_BSTAGE(1, 224)  QKV_COMPUTE(1, 2)
    // it6: [A192,B192,A224,B224]=12 -> wait(6) completes A192+B192
    WAITN(6); QKV_AWRITEA(0) LGKM0; BAR;
    QKV_COMPUTE(0, 0)
    // it7: [A224,B224]=6 -> wait(0) drains
    WAITN(0); QKV_AWRITEB(1) LGKM0; BAR;
    QKV_COMPUTE(1, 1)

    float loc = 0.f;
#pragma unroll
    for (int j = 0; j < 4; ++j) {
        const int colg = col0 + wc + j * 16 + fr;
        const float bj = bias[colg];
#pragma unroll
        for (int i = 0; i < 4; ++i) {
            const int rowg = row0 + wr + i * 16 + q4 * 4;
            const float cv0 = acc[i][j][0] + bj;
            const float cv1 = acc[i][j][1] + bj;
            const float cv2 = acc[i][j][2] + bj;
            const float cv3 = acc[i][j][3] + bj;
            loc += cv0 * cv0 + cv1 * cv1 + cv2 * cv2 + cv3 * cv3;
            const uint p01 = pkbf(cv0, cv1);
            const uint p23 = pkbf(cv2, cv3);
            C[(size_t)(rowg + 0) * HD + colg] = (ushort)p01;
            C[(size_t)(rowg + 1) * HD + colg] = (ushort)(p01 >> 16);
            C[(size_t)(rowg + 2) * HD + colg] = (ushort)p23;
            C[(size_t)(rowg + 3) * HD + colg] = (ushort)(p23 >> 16);
        }
    }
    if (wsel < 2) {
#pragma unroll
        for (int off = 32; off > 0; off >>= 1) loc += __shfl_down(loc, off, 64);
        __syncthreads();               // all As/Bs reads done before wred alias
        if (l == 0) wred[w] = loc;
        __syncthreads();
        if (t == 0) atomicAdd(&sumsq[wsel], wred[0] + wred[1] + wred[2] + wred[3]);
    }
}

// ---------------------------------------------------------------------------
// K3: kv full-pass MFMA (blocks 0..255: one (b,h), 8 chunks of 64 rows,
// in-register accumulation; 18.4 KB LDS) ∪ vbar (blocks 256..1279, 16B
// loads) ∪ bucket (blocks 1280..3327).
// ---------------------------------------------------------------------------
#define KVP 72
__global__ __launch_bounds__(256) void kv_vbar_bucket(
    const ushort* __restrict__ k16, const ushort* __restrict__ v16,
    ushort* __restrict__ kv16, float* __restrict__ ksum_f, float* __restrict__ vsum_f,
    float* __restrict__ vbar,
    const int* __restrict__ ei, const float* __restrict__ ew,
    const int* __restrict__ deg, const int* __restrict__ offsets,
    int* __restrict__ cursor, int2* __restrict__ pairbuf)
{
    __shared__ ushort kT[64 * KVP];
    __shared__ ushort vT[64 * KVP];
    const int bid = blockIdx.x;
    const int t = threadIdx.x;

    if (bid >= 1280) {   // bucket: CSR fill, packed int2 {row, val}
        const int e = (bid - 1280) * 256 + t;
        const int row = ei[e], col = ei[EE + e];
        const long long prod = (long long)deg[row] * (long long)deg[col];
        float val = 0.f;
        if (prod > 0) val = ew[e] * __frsqrt_rn((float)prod);
        const int pos = atomicAdd(&cursor[col], 1);
        pairbuf[offsets[col] + pos] = make_int2(row, __float_as_int(val));
        return;
    }
    if (bid >= 256) {    // vbar: mean over heads, 8 d/thread, 16B loads
        const int idx = (bid - 256) * 256 + t;   // NN*8 total
        const int n = idx >> 3, d0 = (idx & 7) * 8;
        const ushort* vr = &v16[(size_t)n * HD + d0];
        u16x8 v0 = *(const u16x8*)(vr);
        u16x8 v1 = *(const u16x8*)(vr + 64);
        u16x8 v2 = *(const u16x8*)(vr + 128);
        u16x8 v3 = *(const u16x8*)(vr + 192);
        float o[8];
#pragma unroll
        for (int j = 0; j < 8; ++j)
            o[j] = 0.25f * (bf2f(v0[j]) + bf2f(v1[j]) + bf2f(v2[j]) + bf2f(v3[j]));
        float* vb = &vbar[(size_t)n * DD + d0];
        *(float4*)(vb)     = make_float4(o[0], o[1], o[2], o[3]);
        *(float4*)(vb + 4) = make_float4(o[4], o[5], o[6], o[7]);
        return;
    }

    // ---- kv MFMA: one (b,h), all 512 rows in 8 chunks of 64 ----
    const int h = bid & 3, b = bid >> 2;
    const int l = t & 63, w = t >> 6;
    const size_t base = (size_t)b * MM * HD + (size_t)h * DD;

    const int fr = l & 15, q4 = l >> 4, kg = q4 * 8;
    const int wr2 = (w & 1) * 32, wc2 = (w >> 1) * 32;
    s16x8 ones;
#pragma unroll
    for (int i = 0; i < 8; ++i) ones[i] = (short)0x3F80;

    f32x4 acc[2][2] = {};
    f32x4 aks[2] = {};
    f32x4 avs[2] = {};

    // staging decomposition (constant across chunks)
    const int mat = t >> 7;
    const int rem = t & 127;
    const int dq  = rem >> 5;          // 0..3
    const int u   = rem & 31;          // row-pair index
    const int r0  = 2 * u;             // rows r0, r0+1 within chunk
    const int d0  = dq * 16;
    const ushort* src = mat ? v16 : k16;
    ushort* dst = mat ? vT : kT;

    for (int chunk = 0; chunk < 8; ++chunk) {
        const int m0 = chunk * 64;
        {   // transpose-stage 64 rows x 64 d (2 rows/thread, packed uint)
            const ushort* p0 = &src[base + (size_t)(m0 + r0) * HD + d0];
            const ushort* p1 = p0 + HD;
            u16x8 ra0 = *(const u16x8*)(p0);
            u16x8 ra1 = *(const u16x8*)(p0 + 8);
            u16x8 rb0 = *(const u16x8*)(p1);
            u16x8 rb1 = *(const u16x8*)(p1 + 8);
#pragma unroll
            for (int jj = 0; jj < 8; ++jj) {
                uint pk = (uint)ra0[jj] | ((uint)rb0[jj] << 16);
                *(uint*)&dst[(d0 + jj) * KVP + r0] = pk;
            }
#pragma unroll
            for (int jj = 0; jj < 8; ++jj) {
                uint pk = (uint)ra1[jj] | ((uint)rb1[jj] << 16);
                *(uint*)&dst[(d0 + 8 + jj) * KVP + r0] = pk;
            }
        }
        __syncthreads();

#pragma unroll
        for (int s = 0; s < 2; ++s) {
            const int mo = s * 32 + kg;
            s16x8 af[2], bf[2];
            af[0] = *(const s16x8*)&kT[(wr2 + fr) * KVP + mo];
            af[1] = *(const s16x8*)&kT[(wr2 + 16 + fr) * KVP + mo];
            bf[0] = *(const s16x8*)&vT[(wc2 + fr) * KVP + mo];
            bf[1] = *(const s16x8*)&vT[(wc2 + 16 + fr) * KVP + mo];
#pragma unroll
            for (int il = 0; il < 2; ++il)
#pragma unroll
                for (int jl = 0; jl < 2; ++jl)
                    acc[il][jl] = __builtin_amdgcn_mfma_f32_16x16x32_bf16(
                        af[il], bf[jl], acc[il][jl], 0, 0, 0);
#pragma unroll
            for (int il = 0; il < 2; ++il)
                aks[il] = __builtin_amdgcn_mfma_f32_16x16x32_bf16(
                    af[il], ones, aks[il], 0, 0, 0);
#pragma unroll
            for (int jl = 0; jl < 2; ++jl)
                avs[jl] = __builtin_amdgcn_mfma_f32_16x16x32_bf16(
                    ones, bf[jl], avs[jl], 0, 0, 0);
        }
        __syncthreads();   // protect LDS overwrite by next chunk
    }

    // epilogue: kv16 bf16 direct, transposed [dv][dk]
    ushort* kvb = &kv16[((size_t)b * HH + h) * 4096];
#pragma unroll
    for (int jl = 0; jl < 2; ++jl) {
        const int dv = wc2 + 16 * jl + fr;
#pragma unroll
        for (int il = 0; il < 2; ++il) {
            const int dk = wr2 + 16 * il + q4 * 4;
            uint2 pk = make_uint2(pkbf(acc[il][jl][0], acc[il][jl][1]),
                                  pkbf(acc[il][jl][2], acc[il][jl][3]));
            *(uint2*)&kvb[(size_t)dv * 64 + dk] = pk;
        }
    }
    float* ksb = &ksum_f[((size_t)b * HH + h) * 64];
    float* vsb = &vsum_f[((size_t)b * HH + h) * 64];
    if (wc2 == 0 && fr == 0) {
#pragma unroll
        for (int il = 0; il < 2; ++il)
#pragma unroll
            for (int m = 0; m < 4; ++m)
                ksb[wr2 + 16 * il + q4 * 4 + m] = aks[il][m];
    }
    if (wr2 == 0 && l < 16) {
        vsb[wc2 + l]      = avs[0][0];
        vsb[wc2 + 16 + l] = avs[1][0];
    }
}

// ---------------------------------------------------------------------------
// K5: attn via MFMA. All 4 heads' KV + sums staged once; all 256
// denominators in one phase; head loop pure MFMA+epilogue, 2 barriers.
// ---------------------------------------------------------------------------
#define AKP 72
__global__ __launch_bounds__(256) void attn_mfma(
    const ushort* __restrict__ q16, const ushort* __restrict__ kv16,
    const float* __restrict__ ksum_f, const float* __restrict__ vsum_f,
    const float* __restrict__ sumsq,
    const int* __restrict__ n_nodes, float* __restrict__ out)
{
    const int b = blockIdx.y;
    const int m0 = blockIdx.x * 64;
    const int t = threadIdx.x;
    const int l = t & 63, w = t >> 6;
    const int fr = l & 15, q4 = l >> 4;
    const int wn = (w & 1) * 32, wd = (w >> 1) * 32;

    __shared__ ushort kvbf[HH][64 * AKP];
    __shared__ float ksum_l[HH][64], vsum_l[HH][64], denom_l[HH][64];

    const float nn = (float)n_nodes[b];
    const float inv = 1.0f / (sqrtf(sumsq[0]) * sqrtf(sumsq[1]));

    {   // stage all heads: bf16 KV [dv][dk] + ksum/vsum
        const int dv = t >> 2, dk0 = (t & 3) * 16;
#pragma unroll
        for (int h = 0; h < HH; ++h) {
            const ushort* kvg = &kv16[((size_t)(b * HH + h)) * 4096 + dv * 64 + dk0];
            *(uint4*)&kvbf[h][dv * AKP + dk0]     = *(const uint4*)kvg;
            *(uint4*)&kvbf[h][dv * AKP + dk0 + 8] = *(const uint4*)(kvg + 8);
        }
        const int hh = t >> 6, dd = t & 63;
        ksum_l[hh][dd] = ksum_f[((size_t)(b * HH + hh)) * 64 + dd];
        vsum_l[hh][dd] = vsum_f[((size_t)(b * HH + hh)) * 64 + dd];
    }
    __syncthreads();

    {   // denominators, all heads at once: thread = (row r, head hh)
        const int r = t & 63, hh = t >> 6;
        const ushort* qr = &q16[((size_t)(b * MM + m0 + r)) * HD + hh * DD];
        float dsum = 0.f;
#pragma unroll
        for (int c = 0; c < 8; ++c) {
            u16x8 qv = *(const u16x8*)(qr + 8 * c);
#pragma unroll
            for (int j2 = 0; j2 < 8; ++j2)
                dsum += bf2f(qv[j2]) * ksum_l[hh][8 * c + j2];
        }
        denom_l[hh][r] = nn + inv * dsum;
    }
    __syncthreads();

    f32x4 acco[2][2] = {};
#pragma unroll
    for (int h = 0; h < HH; ++h) {
        f32x4 pacc[2][2] = {};
#pragma unroll
        for (int kx = 0; kx < 2; ++kx) {
            const int k0 = kx * 32;
            s16x8 af[2], bfr[2];
#pragma unroll
            for (int il = 0; il < 2; ++il)
                af[il] = *(const s16x8*)&q16[
                    ((size_t)(b * MM + m0 + wn + 16 * il + fr)) * HD + h * DD + k0 + q4 * 8];
#pragma unroll
            for (int jl = 0; jl < 2; ++jl)
                bfr[jl] = *(const s16x8*)&kvbf[h][(wd + 16 * jl + fr) * AKP + k0 + q4 * 8];
#pragma unroll
            for (int il = 0; il < 2; ++il)
#pragma unroll
                for (int jl = 0; jl < 2; ++jl)
                    pacc[il][jl] = __builtin_amdgcn_mfma_f32_16x16x32_bf16(
                        af[il], bfr[jl], pacc[il][jl], 0, 0, 0);
        }
#pragma unroll
        for (int il = 0; il < 2; ++il)
#pragma unroll
            for (int m = 0; m < 4; ++m) {
                const float rden = 0.25f / denom_l[h][wn + 16 * il + q4 * 4 + m];
#pragma unroll
                for (int jl = 0; jl < 2; ++jl) {
                    const int d = wd + 16 * jl + fr;
                    acco[il][jl][m] += (inv * pacc[il][jl][m] + vsum_l[h][d]) * rden;
                }
            }
    }

#pragma unroll
    for (int il = 0; il < 2; ++il)
#pragma unroll
        for (int m = 0; m < 4; ++m) {
            const size_t node = (size_t)b * MM + m0 + wn + 16 * il + q4 * 4 + m;
#pragma unroll
            for (int jl = 0; jl < 2; ++jl)
                out[node * DD + wd + 16 * jl + fr] = acco[il][jl][m];
        }
}

// ---------------------------------------------------------------------------
// K6: GCN gather, 32 threads/node (2 groups of 16 split even/odd edges,
// combine via shfl_xor 16).
// ---------------------------------------------------------------------------
__global__ __launch_bounds__(256) void gcn_gather(
    const int* __restrict__ offsets, const int2* __restrict__ pairbuf,
    const float* __restrict__ vbar, float* __restrict__ out)
{
    const int t = blockIdx.x * 256 + threadIdx.x;   // NN*32 threads
    const int n = t >> 5;
    const int g = t & 31;
    const int d4 = (g & 15) << 2;
    const int grp = g >> 4;
    const int s = offsets[n], e = offsets[n + 1];
    float ax = 0.f, ay = 0.f, az = 0.f, aw = 0.f;
    int i = s + grp;
    for (; i + 2 < e; i += 4) {   // two edges (stride-2 within group)
        const int2 p0 = pairbuf[i], p1 = pairbuf[i + 2];
        const float w0 = __int_as_float(p0.y), w1 = __int_as_float(p1.y);
        const float4 v0 = *(const float4*)&vbar[(size_t)p0.x * DD + d4];
        const float4 v1 = *(const float4*)&vbar[(size_t)p1.x * DD + d4];
        ax += w0 * v0.x + w1 * v1.x;
        ay += w0 * v0.y + w1 * v1.y;
        az += w0 * v0.z + w1 * v1.z;
        aw += w0 * v0.w + w1 * v1.w;
    }
    if (i < e) {
        const int2 p = pairbuf[i];
        const float wv = __int_as_float(p.y);
        const float4 v = *(const float4*)&vbar[(size_t)p.x * DD + d4];
        ax += wv * v.x; ay += wv * v.y; az += wv * v.z; aw += wv * v.w;
    }
    ax += __shfl_xor(ax, 16, 64);
    ay += __shfl_xor(ay, 16, 64);
    az += __shfl_xor(az, 16, 64);
    aw += __shfl_xor(aw, 16, 64);
    if (grp == 0) {
        float4 o = *(float4*)&out[(size_t)n * DD + d4];
        o.x += ax; o.y += ay; o.z += az; o.w += aw;
        *(float4*)&out[(size_t)n * DD + d4] = o;
    }
}

// ---------------------------------------------------------------------------
extern "C" void kernel_launch(void* const* d_in, const int* in_sizes, int n_in,
                              void* d_out, int out_size, void* d_ws, size_t ws_size,
                              hipStream_t stream)
{
    (void)in_sizes; (void)n_in; (void)out_size; (void)ws_size;
    const float* Xq = (const float*)d_in[0];
    const float* Xs = (const float*)d_in[1];
    const float* ew = (const float*)d_in[2];
    const float* Wq = (const float*)d_in[3];
    const float* bq = (const float*)d_in[4];
    const float* Wk = (const float*)d_in[5];
    const float* bk = (const float*)d_in[6];
    const float* Wv = (const float*)d_in[7];
    const float* bv = (const float*)d_in[8];
    const int* n_nodes = (const int*)d_in[9];
    const int* ei = (const int*)d_in[10];
    float* out = (float*)d_out;
    float* ws  = (float*)d_ws;

    // workspace layout (float units); q/k/v bf16
    const size_t SZ_QKV   = (size_t)NN * HD / 2;       // 4194304 each
    const size_t OFF_Q    = 0;
    const size_t OFF_K    = SZ_QKV;
    const size_t OFF_V    = SZ_QKV * 2;
    const size_t OFF_SS   = SZ_QKV * 3;                // 16 floats (zeroed)
    const size_t OFF_DEG  = OFF_SS + 16;               // NN ints (zeroed)
    const size_t OFF_CUR  = OFF_DEG + NN;              // NN ints (zeroed)
    const size_t OFF_WT   = OFF_CUR + NN;              // 3*65536 ushorts
    const size_t OFF_OFFS = OFF_WT + 3 * 65536 / 2;    // NN+1 (+pad)
    const size_t OFF_KV16 = OFF_OFFS + NN + 16;                       // 524288 bf16
    const size_t OFF_KSF  = OFF_KV16 + (size_t)BB * HH * 4096 / 2;    // 16384
    const size_t OFF_VSF  = OFF_KSF + (size_t)BB * HH * 64;           // 16384
    const size_t OFF_PAIR = OFF_VSF + (size_t)BB * HH * 64;           // 1048576
    const size_t OFF_VBAR = OFF_PAIR + 2 * (size_t)EE;                // 2097152
    // total ≈ 66 MB

    ushort* q16   = (ushort*)(ws + OFF_Q);
    ushort* k16   = (ushort*)(ws + OFF_K);
    ushort* v16   = (ushort*)(ws + OFF_V);
    float* sumsq  = ws + OFF_SS;
    int*   deg    = (int*)(ws + OFF_DEG);
    int*   cursor = (int*)(ws + OFF_CUR);
    ushort* WT    = (ushort*)(ws + OFF_WT);
    int*   offs   = (int*)(ws + OFF_OFFS);
    ushort* kv16  = (ushort*)(ws + OFF_KV16);
    float* ksum_f = ws + OFF_KSF;
    float* vsum_f = ws + OFF_VSF;
    int2*  pairb  = (int2*)(ws + OFF_PAIR);
    float* vbar   = ws + OFF_VBAR;

    // zero sumsq + deg + cursor (contiguous)
    hipMemsetAsync(sumsq, 0, (16 + 2 * NN) * sizeof(float), stream);
    prep_kernel<<<2816, 256, 0, stream>>>(Wq, Wk, Wv, WT, ei, deg);
    qkv_scan<<<1537, 256, 0, stream>>>(
        Xq, Xs, WT, bq, bk, bv, q16, k16, v16, sumsq, deg, offs);
    kv_vbar_bucket<<<3328, 256, 0, stream>>>(
        k16, v16, kv16, ksum_f, vsum_f, vbar, ei, ew, deg, offs, cursor, pairb);
    attn_mfma<<<dim3(MM / 64, BB), 256, 0, stream>>>(
        q16, kv16, ksum_f, vsum_f, sumsq, n_nodes, out);
    gcn_gather<<<(NN * 32) / 256, 256, 0, stream>>>(offs, pairb, vbar, out);
}